// Round 13
// baseline (65313.434 us; speedup 1.0000x reference)
//
#include <hip/hip_runtime.h>
#include <math.h>

#define TPB     128
#define NBATCH  64
#define SPB     16
#define NBLK    (NBATCH*SPB)       // 1024 blocks — the proven topology
#define SROWS   16
#define MM      256
#define AN      257
#define NITER   300
#define NIT1    (NITER+1)
#define SARR    (NBATCH*NIT1)      // ints per counter/flag array
#define RS      264
#define CO(k)   ((k) + ((k) >> 5))

typedef float v4f __attribute__((ext_vector_type(4)));

// ---- contraction-proof IEEE fp32 ops (trajectory bit-identical to round 0/10/12).
__device__ __forceinline__ float mulf(float a, float b) {
  float d; asm("v_mul_f32 %0, %1, %2" : "=v"(d) : "v"(a), "v"(b)); return d;
}
__device__ __forceinline__ float addf(float a, float b) {
  float d; asm("v_add_f32 %0, %1, %2" : "=v"(d) : "v"(a), "v"(b)); return d;
}
__device__ __forceinline__ float subf(float a, float b) {
  float d; asm("v_sub_f32 %0, %1, %2" : "=v"(d) : "v"(a), "v"(b)); return d;
}
__device__ __forceinline__ float fmacf(float acc, float x, float y) {
  asm("v_fmac_f32 %0, %1, %2" : "+v"(acc) : "v"(x), "v"(y)); return acc;
}

// ---- coherent transport: per-access LLC-coherent, cache-bypassing, vectorized.
__device__ __forceinline__ v4f ld4c(const float* p) {
  v4f r;
  asm volatile("global_load_dwordx4 %0, %1, off sc0 sc1" : "=v"(r) : "v"(p) : "memory");
  return r;
}
__device__ __forceinline__ void st4c(float* p, v4f v) {
  asm volatile("global_store_dwordx4 %0, %1, off sc0 sc1" :: "v"(p), "v"(v) : "memory");
}
__device__ __forceinline__ void vmdrain()  { asm volatile("s_waitcnt vmcnt(0)" ::: "memory"); }
__device__ __forceinline__ void drain_all(){ asm volatile("s_waitcnt vmcnt(0) lgkmcnt(0)" ::: "memory"); }

// ---- round-0-proven sync: RELAXED atomics + explicit drains.
#define ALD_F(p)    __hip_atomic_load((p),  __ATOMIC_RELAXED, __HIP_MEMORY_SCOPE_AGENT)
#define AST_F(p,v)  __hip_atomic_store((p), (v), __ATOMIC_RELAXED, __HIP_MEMORY_SCOPE_AGENT)
#define ALD_I(p)    __hip_atomic_load((p),  __ATOMIC_RELAXED, __HIP_MEMORY_SCOPE_AGENT)
#define AST_I(p,v)  __hip_atomic_store((p), (v), __ATOMIC_RELAXED, __HIP_MEMORY_SCOPE_AGENT)
#define AADD_I(p)   __hip_atomic_fetch_add((p), 1, __ATOMIC_RELAXED, __HIP_MEMORY_SCOPE_AGENT)

__global__ void init_ws_kernel(int* __restrict__ z, int n) {
  int i = blockIdx.x * blockDim.x + threadIdx.x;
  if (i < n) z[i] = 0;
}

__device__ __forceinline__ void waitEq(int* p, int target) {
  int tries = 0;
  while (ALD_I(p) < target) {
    __builtin_amdgcn_s_sleep(2);
    if (++tries > (1 << 22)) break;   // hang-safety valve (never expected)
  }
}

// =============== two-wave pair-split dot (round-10 verbatim, proven) ===============
#define W2_FMA16 \
    if (lw < 16) { \
      _Pragma("unroll") \
      for (int cj = 0; cj < 16; ++cj) \
        acc = fmacf(acc, sW[cj * 16 + lw], sW[256 + cj * 16 + lw]); \
    }

#define W2_STEP(D) { \
    asm volatile("s_waitcnt vmcnt(14)" ::: "memory"); \
    *(v4f*)&sW[wix]       = xq[D]; \
    *(v4f*)&sW[256 + wix] = yq[D]; \
    asm volatile("s_waitcnt lgkmcnt(0)" ::: "memory"); \
    xq[D] = ld4c(xp + (size_t)(P0 + (D) + 8) * 512); \
    yq[D] = ld4c(yp + (size_t)(P0 + (D) + 8) * 512); \
    W2_FMA16 \
    asm volatile("s_waitcnt lgkmcnt(0)" ::: "memory"); }

#define W2_TAIL(D, VM) { \
    asm volatile("s_waitcnt vmcnt(" #VM ")" ::: "memory"); \
    *(v4f*)&sW[wix]       = xq[D]; \
    *(v4f*)&sW[256 + wix] = yq[D]; \
    asm volatile("s_waitcnt lgkmcnt(0)" ::: "memory"); \
    W2_FMA16 \
    asm volatile("s_waitcnt lgkmcnt(0)" ::: "memory"); }

__device__ float dot2w(const float* __restrict__ X, const float* __restrict__ Y,
                       float* __restrict__ sDot, float* __restrict__ sAcc, int tid) {
  const int lw  = tid & 63;
  const int wid = tid >> 6;
  float* sW = sDot + wid * 512;
  const int off = (lw >> 2) * 32 + (lw & 3) * 4 + wid * 16;
  const int wix = (lw >> 2) * 16 + (lw & 3) * 4;
  const float* xp = X + off;
  const float* yp = Y + off;
  v4f xq[8], yq[8];
  #pragma unroll
  for (int d = 0; d < 8; ++d) {
    xq[d] = ld4c(xp + (size_t)d * 512);
    yq[d] = ld4c(yp + (size_t)d * 512);
  }
  float acc = 0.0f;
  #pragma unroll 1
  for (int g = 0; g < 15; ++g) {
    const int P0 = g * 8;
    W2_STEP(0) W2_STEP(1) W2_STEP(2) W2_STEP(3)
    W2_STEP(4) W2_STEP(5) W2_STEP(6) W2_STEP(7)
  }
  W2_TAIL(0, 14) W2_TAIL(1, 12) W2_TAIL(2, 10) W2_TAIL(3, 8)
  W2_TAIL(4, 6)  W2_TAIL(5, 4)  W2_TAIL(6, 2)  W2_TAIL(7, 0)

  if (lw < 16) sAcc[wid * 16 + lw] = acc;
  __syncthreads();
  float d0[32];
  #pragma unroll
  for (int o = 0; o < 32; ++o) d0[o] = sAcc[o];
  float C[8];
  #pragma unroll
  for (int l = 0; l < 8; ++l)
    C[l] = addf(addf(d0[l], d0[8 + l]), addf(d0[16 + l], d0[24 + l]));
  float D[4];
  #pragma unroll
  for (int l = 0; l < 4; ++l) D[l] = addf(C[l], C[l + 4]);
  float res = addf(addf(D[0], D[1]), addf(D[2], D[3]));
  __syncthreads();
  return res;
}

// X==Y variant (round-10 verbatim, proven) — used only at it==1 for gamma0.
#define SQ_FMA16 \
    if (lw < 16) { \
      _Pragma("unroll") \
      for (int cj = 0; cj < 16; ++cj) { \
        float xv = sW[cj * 16 + lw]; \
        acc = fmacf(acc, xv, xv); \
      } \
    }

#define SQ_STEP(D) { \
    asm volatile("s_waitcnt vmcnt(15)" ::: "memory"); \
    *(v4f*)&sW[wix] = xq[D]; \
    asm volatile("s_waitcnt lgkmcnt(0)" ::: "memory"); \
    xq[D] = ld4c(xp + (size_t)(P0 + (D) + 16) * 512); \
    SQ_FMA16 \
    asm volatile("s_waitcnt lgkmcnt(0)" ::: "memory"); }

#define SQ_TAIL(D, VM) { \
    asm volatile("s_waitcnt vmcnt(" #VM ")" ::: "memory"); \
    *(v4f*)&sW[wix] = xq[D]; \
    asm volatile("s_waitcnt lgkmcnt(0)" ::: "memory"); \
    SQ_FMA16 \
    asm volatile("s_waitcnt lgkmcnt(0)" ::: "memory"); }

__device__ float dotSq(const float* __restrict__ X,
                       float* __restrict__ sDot, float* __restrict__ sAcc, int tid) {
  const int lw  = tid & 63;
  const int wid = tid >> 6;
  float* sW = sDot + wid * 512;
  const int off = (lw >> 2) * 32 + (lw & 3) * 4 + wid * 16;
  const int wix = (lw >> 2) * 16 + (lw & 3) * 4;
  const float* xp = X + off;
  v4f xq[16];
  #pragma unroll
  for (int d = 0; d < 16; ++d) xq[d] = ld4c(xp + (size_t)d * 512);
  float acc = 0.0f;
  #pragma unroll 1
  for (int g = 0; g < 7; ++g) {
    const int P0 = g * 16;
    SQ_STEP(0)  SQ_STEP(1)  SQ_STEP(2)  SQ_STEP(3)
    SQ_STEP(4)  SQ_STEP(5)  SQ_STEP(6)  SQ_STEP(7)
    SQ_STEP(8)  SQ_STEP(9)  SQ_STEP(10) SQ_STEP(11)
    SQ_STEP(12) SQ_STEP(13) SQ_STEP(14) SQ_STEP(15)
  }
  SQ_TAIL(0, 15)  SQ_TAIL(1, 14)  SQ_TAIL(2, 13)  SQ_TAIL(3, 12)
  SQ_TAIL(4, 11)  SQ_TAIL(5, 10)  SQ_TAIL(6, 9)   SQ_TAIL(7, 8)
  SQ_TAIL(8, 7)   SQ_TAIL(9, 6)   SQ_TAIL(10, 5)  SQ_TAIL(11, 4)
  SQ_TAIL(12, 3)  SQ_TAIL(13, 2)  SQ_TAIL(14, 1)  SQ_TAIL(15, 0)

  if (lw < 16) sAcc[wid * 16 + lw] = acc;
  __syncthreads();
  float d0[32];
  #pragma unroll
  for (int o = 0; o < 32; ++o) d0[o] = sAcc[o];
  float C[8];
  #pragma unroll
  for (int l = 0; l < 8; ++l)
    C[l] = addf(addf(d0[l], d0[8 + l]), addf(d0[16 + l], d0[24 + l]));
  float D[4];
  #pragma unroll
  for (int l = 0; l < 4; ++l) D[l] = addf(C[l], C[l + 4]);
  float res = addf(addf(D[0], D[1]), addf(D[2], D[3]));
  __syncthreads();
  return res;
}

// ===== dotRR: r_new·r_new where r_new = r_old − α·Ap, computed IN-CHAIN. =====
// Structure = dot2w verbatim (X=r_old, Y=Ap); chain lanes compute
// rn = subf(x, mulf(alfv, y)) — the EXACT slab phase-B ops on the EXACT bits —
// then fmac(acc, rn, rn): identical values, identical slot/order chain as
// dotSq over the slab-published r_new. Bit-identical gamma'.
#define RR_FMA16 \
    if (lw < 16) { \
      _Pragma("unroll") \
      for (int cj = 0; cj < 16; ++cj) { \
        float xv = sW[cj * 16 + lw]; \
        float yv = sW[256 + cj * 16 + lw]; \
        float rn = subf(xv, mulf(alfv, yv)); \
        acc = fmacf(acc, rn, rn); \
      } \
    }

#define RR_STEP(D) { \
    asm volatile("s_waitcnt vmcnt(14)" ::: "memory"); \
    *(v4f*)&sW[wix]       = xq[D]; \
    *(v4f*)&sW[256 + wix] = yq[D]; \
    asm volatile("s_waitcnt lgkmcnt(0)" ::: "memory"); \
    xq[D] = ld4c(xp + (size_t)(P0 + (D) + 8) * 512); \
    yq[D] = ld4c(yp + (size_t)(P0 + (D) + 8) * 512); \
    RR_FMA16 \
    asm volatile("s_waitcnt lgkmcnt(0)" ::: "memory"); }

#define RR_TAIL(D, VM) { \
    asm volatile("s_waitcnt vmcnt(" #VM ")" ::: "memory"); \
    *(v4f*)&sW[wix]       = xq[D]; \
    *(v4f*)&sW[256 + wix] = yq[D]; \
    asm volatile("s_waitcnt lgkmcnt(0)" ::: "memory"); \
    RR_FMA16 \
    asm volatile("s_waitcnt lgkmcnt(0)" ::: "memory"); }

__device__ float dotRR(const float* __restrict__ X, const float* __restrict__ Y,
                       float alfv,
                       float* __restrict__ sDot, float* __restrict__ sAcc, int tid) {
  const int lw  = tid & 63;
  const int wid = tid >> 6;
  float* sW = sDot + wid * 512;
  const int off = (lw >> 2) * 32 + (lw & 3) * 4 + wid * 16;
  const int wix = (lw >> 2) * 16 + (lw & 3) * 4;
  const float* xp = X + off;
  const float* yp = Y + off;
  v4f xq[8], yq[8];
  #pragma unroll
  for (int d = 0; d < 8; ++d) {
    xq[d] = ld4c(xp + (size_t)d * 512);
    yq[d] = ld4c(yp + (size_t)d * 512);
  }
  float acc = 0.0f;
  #pragma unroll 1
  for (int g = 0; g < 15; ++g) {
    const int P0 = g * 8;
    RR_STEP(0) RR_STEP(1) RR_STEP(2) RR_STEP(3)
    RR_STEP(4) RR_STEP(5) RR_STEP(6) RR_STEP(7)
  }
  RR_TAIL(0, 14) RR_TAIL(1, 12) RR_TAIL(2, 10) RR_TAIL(3, 8)
  RR_TAIL(4, 6)  RR_TAIL(5, 4)  RR_TAIL(6, 2)  RR_TAIL(7, 0)

  if (lw < 16) sAcc[wid * 16 + lw] = acc;
  __syncthreads();
  float d0[32];
  #pragma unroll
  for (int o = 0; o < 32; ++o) d0[o] = sAcc[o];
  float C[8];
  #pragma unroll
  for (int l = 0; l < 8; ++l)
    C[l] = addf(addf(d0[l], d0[8 + l]), addf(d0[16 + l], d0[24 + l]));
  float D[4];
  #pragma unroll
  for (int l = 0; l < 4; ++l) D[l] = addf(C[l], C[l + 4]);
  float res = addf(addf(D[0], D[1]), addf(D[2], D[3]));
  __syncthreads();
  return res;
}

__launch_bounds__(TPB, 2)   // the proven cap (rounds 0/6/10/12)
__global__ void cg_kernel(const float* __restrict__ alpha,
                          const float* __restrict__ frhs,
                          float* __restrict__ out,
                          int* __restrict__ Z,
                          float* __restrict__ av,
                          float* __restrict__ bv,
                          float* __restrict__ halo,
                          float* __restrict__ pbuf,
                          float* __restrict__ apbuf,
                          float* __restrict__ rbuf)
{
  __shared__ float sP[(SROWS + 2) * RS];
  __shared__ __align__(16) float sDot[1024];
  __shared__ float sAcc[32];

  int* cntP  = Z + 0 * SARR;
  int* cntA  = Z + 1 * SARR;
  int* flg   = Z + 3 * SARR;   // single alpha+beta flag (cntB/flagB edges removed)

  const int tid  = threadIdx.x;
  const int bx   = blockIdx.x;
  const int b    = bx >> 4;
  const int s    = bx & 15;
  const int js   = s * SROWS;
  const int jloc = tid >> 3;
  const int k0   = (tid & 7) << 5;
  const int jg   = js + jloc;
  const int rowb = (jloc + 1) * RS;
  const int bNI  = b * NIT1;
  const size_t gbase = (size_t)b * (MM * MM) + (size_t)jg * MM + k0;

  // ---- coefficients once (round-12 verbatim, bit-identical)
  float kl[32], kr[32], kbx[33], dg[32];
  {
    const float* r0 = alpha + (size_t)b * (AN * AN) + (size_t)jg * AN + k0;
    const float* r1 = r0 + AN;
    float a0[33], a1[33];
    #pragma unroll
    for (int i = 0; i < 33; ++i) { a0[i] = r0[i]; a1[i] = r1[i]; }
    #pragma unroll
    for (int i = 0; i < 33; ++i) kbx[i] = expf(0.5f * (a0[i] + a1[i]));
    #pragma unroll
    for (int i = 0; i < 32; ++i) {
      const int kg = k0 + i;
      float vkl = expf(0.5f * (a0[i] + a0[i + 1]));
      float vkr = (jg < MM - 1) ? expf(0.5f * (a1[i] + a1[i + 1])) : 0.0f;
      float vkb = (kg > 0)      ? kbx[i]     : 0.0f;
      float vkt = (kg < MM - 1) ? kbx[i + 1] : 0.0f;
      float d = ((vkl + vkr) + vkb) + vkt;
      if (jg == 0) d += vkl;
      kl[i] = vkl; kr[i] = vkr; dg[i] = d;
    }
  }

  float uu[32], rr[32], pp[32], Ap[32];
  {
    const float* fB = frhs + (size_t)jg * MM + k0;
    #pragma unroll
    for (int i = 0; i < 32; ++i) {
      float v = fB[i];
      uu[i] = 0.0f; rr[i] = v; pp[i] = v;
      sP[rowb + CO(k0 + i)] = v;
    }
    #pragma unroll
    for (int q = 0; q < 8; ++q) {
      v4f pv; pv[0] = pp[4*q]; pv[1] = pp[4*q+1]; pv[2] = pp[4*q+2]; pv[3] = pp[4*q+3];
      st4c(&pbuf[gbase + 4 * q], pv);
      st4c(&rbuf[gbase + 4 * q], pv);
    }
  }
  float* myhalo = halo + (size_t)bx * 512;
  if (jloc == 0) {
    #pragma unroll
    for (int q = 0; q < 8; ++q) {
      v4f hv; hv[0] = pp[4*q]; hv[1] = pp[4*q+1]; hv[2] = pp[4*q+2]; hv[3] = pp[4*q+3];
      st4c(&myhalo[k0 + 4 * q], hv);
    }
  }
  if (jloc == SROWS - 1) {
    #pragma unroll
    for (int q = 0; q < 8; ++q) {
      v4f hv; hv[0] = pp[4*q]; hv[1] = pp[4*q+1]; hv[2] = pp[4*q+2]; hv[3] = pp[4*q+3];
      st4c(&myhalo[256 + k0 + 4 * q], hv);
    }
  }
  drain_all();
  __syncthreads();
  if (tid == 0) AADD_I(&cntP[bNI + 0]);

  float gamma_red = 0.0f;   // uniform across the s==0 block after dots

  for (int it = 1; it <= NITER; ++it) {
    // ---- phase A: wait p ready, stage halos, stencil, publish Ap
    if (tid == 0) waitEq(&cntP[bNI + it - 1], SPB);
    __syncthreads();
    if (jloc == 0) {
      if (s > 0) {
        float* nh = halo + (size_t)(bx - 1) * 512 + 256;
        v4f hv[8];
        #pragma unroll
        for (int q = 0; q < 8; ++q) hv[q] = ld4c(&nh[k0 + 4 * q]);
        vmdrain();
        #pragma unroll
        for (int q = 0; q < 8; ++q) {
          sP[CO(k0 + 4*q)]     = hv[q][0];
          sP[CO(k0 + 4*q + 1)] = hv[q][1];
          sP[CO(k0 + 4*q + 2)] = hv[q][2];
          sP[CO(k0 + 4*q + 3)] = hv[q][3];
        }
      } else {
        #pragma unroll
        for (int i = 0; i < 32; ++i) sP[CO(k0 + i)] = 0.0f;
      }
    }
    if (jloc == SROWS - 1) {
      if (s < SPB - 1) {
        float* nh = halo + (size_t)(bx + 1) * 512;
        v4f hv[8];
        #pragma unroll
        for (int q = 0; q < 8; ++q) hv[q] = ld4c(&nh[k0 + 4 * q]);
        vmdrain();
        #pragma unroll
        for (int q = 0; q < 8; ++q) {
          sP[(SROWS + 1) * RS + CO(k0 + 4*q)]     = hv[q][0];
          sP[(SROWS + 1) * RS + CO(k0 + 4*q + 1)] = hv[q][1];
          sP[(SROWS + 1) * RS + CO(k0 + 4*q + 2)] = hv[q][2];
          sP[(SROWS + 1) * RS + CO(k0 + 4*q + 3)] = hv[q][3];
        }
      } else {
        #pragma unroll
        for (int i = 0; i < 32; ++i) sP[(SROWS + 1) * RS + CO(k0 + i)] = 0.0f;
      }
    }
    __syncthreads();

    {
      v4f apv;
      #pragma unroll
      for (int i = 0; i < 32; ++i) {
        const int kg = k0 + i;
        float pc = pp[i];
        float pd = sP[rowb - RS + CO(kg)];
        float pu = sP[rowb + RS + CO(kg)];
        float pl = (i > 0) ? pp[i - 1]
                           : ((k0 > 0) ? sP[rowb + CO(k0 - 1)] : 0.0f);
        float pr = (i < 31) ? pp[i + 1]
                            : ((kg < MM - 1) ? sP[rowb + CO(k0 + 32)] : 0.0f);
        float vkb = (kg > 0)      ? kbx[i]     : 0.0f;
        float vkt = (kg < MM - 1) ? kbx[i + 1] : 0.0f;
        float t = mulf(dg[i], pc);
        t = subf(t, mulf(kl[i], pd));
        t = subf(t, mulf(kr[i], pu));
        t = subf(t, mulf(vkb, pl));
        t = subf(t, mulf(vkt, pr));
        float ap = mulf(65536.0f, t);
        Ap[i] = ap;
        apv[i & 3] = ap;
        if ((i & 3) == 3) st4c(&apbuf[gbase + (i - 3)], apv);
      }
    }
    drain_all();
    __syncthreads();
    if (tid == 0) AADD_I(&cntA[bNI + it]);

    // ---- reducer (block s==0): alpha AND beta behind ONE flag.
    // beta needs no slab publication: r_new is recomputed in-chain from
    // rbuf (r_old, round-(it-1) bits) + apbuf + alpha — bit-identical.
    if (s == 0) {
      if (tid == 0) waitEq(&cntA[bNI + it], SPB);
      __syncthreads();
      const float* Pb  = pbuf  + (size_t)b * (MM * MM);
      const float* APb = apbuf + (size_t)b * (MM * MM);
      const float* Rb  = rbuf  + (size_t)b * (MM * MM);
      if (it == 1) gamma_red = dotSq(Rb, sDot, sAcc, tid);
      float pap  = dot2w(Pb, APb, sDot, sAcc, tid);
      float alfr = gamma_red / pap;                     // uniform, = av bits
      float g2   = dotRR(Rb, APb, alfr, sDot, sAcc, tid);
      if (tid == 0) {
        AST_F(&av[bNI + it], alfr);
        AST_F(&bv[bNI + it], g2 / gamma_red);
        vmdrain();
        AST_I(&flg[bNI + it], 1);
      }
      gamma_red = g2;
    }

    // ---- merged phase B+C: u += a p ; r -= a Ap ; p = r + b p ; publish r,p,halos
    if (tid == 0) waitEq(&flg[bNI + it], 1);
    __syncthreads();
    float alf = ALD_F(&av[bNI + it]);
    float bet = ALD_F(&bv[bNI + it]);
    {
      v4f rv;
      #pragma unroll
      for (int i = 0; i < 32; ++i) {
        uu[i] = addf(uu[i], mulf(alf, pp[i]));
        rr[i] = subf(rr[i], mulf(alf, Ap[i]));
        rv[i & 3] = rr[i];
        if ((i & 3) == 3) st4c(&rbuf[gbase + (i - 3)], rv);
      }
    }
    {
      v4f pv;
      #pragma unroll
      for (int i = 0; i < 32; ++i) {
        float pn = addf(rr[i], mulf(bet, pp[i]));
        pp[i] = pn;
        sP[rowb + CO(k0 + i)] = pn;
        pv[i & 3] = pn;
        if ((i & 3) == 3) st4c(&pbuf[gbase + (i - 3)], pv);
      }
    }
    if (jloc == 0) {
      #pragma unroll
      for (int q = 0; q < 8; ++q) {
        v4f hv; hv[0] = pp[4*q]; hv[1] = pp[4*q+1]; hv[2] = pp[4*q+2]; hv[3] = pp[4*q+3];
        st4c(&myhalo[k0 + 4 * q], hv);
      }
    }
    if (jloc == SROWS - 1) {
      #pragma unroll
      for (int q = 0; q < 8; ++q) {
        v4f hv; hv[0] = pp[4*q]; hv[1] = pp[4*q+1]; hv[2] = pp[4*q+2]; hv[3] = pp[4*q+3];
        st4c(&myhalo[256 + k0 + 4 * q], hv);
      }
    }
    drain_all();
    __syncthreads();
    if (tid == 0) AADD_I(&cntP[bNI + it]);
  }

  float* oB = out + gbase;
  #pragma unroll
  for (int i = 0; i < 32; ++i) oB[i] = uu[i];
}

extern "C" void kernel_launch(void* const* d_in, const int* in_sizes, int n_in,
                              void* d_out, int out_size, void* d_ws, size_t ws_size,
                              hipStream_t stream) {
  const float* alpha = (const float*)d_in[0];   // (64, 257, 257) fp32
  const float* frhs  = (const float*)d_in[1];   // (256, 256) fp32
  float* out = (float*)d_out;                   // (64, 256, 256) fp32

  char* ws = (char*)d_ws;
  int*   Z    = (int*)ws;                               // 5 int arrays [64][301]
  float* av   = (float*)(ws + (size_t)5 * SARR * 4);
  float* bv   = (float*)(ws + (size_t)6 * SARR * 4);
  size_t ZR   = ((size_t)7 * SARR * 4 + 4095) & ~(size_t)4095;
  float* halo  = (float*)(ws + ZR);                     // 2 MB
  float* pbuf  = (float*)(ws + ZR + (size_t)NBLK * 512 * 4);
  float* apbuf = pbuf  + (size_t)NBATCH * MM * MM;      // 16 MB each
  float* rbuf  = apbuf + (size_t)NBATCH * MM * MM;

  int nz = 5 * SARR;
  hipLaunchKernelGGL(init_ws_kernel, dim3((nz + 255) / 256), dim3(256), 0, stream,
                     Z, nz);
  hipLaunchKernelGGL(cg_kernel, dim3(NBLK), dim3(TPB), 0, stream,
                     alpha, frhs, out, Z, av, bv, halo, pbuf, apbuf, rbuf);
}

// Round 14
// 40906.247 us; speedup vs baseline: 1.5967x; 1.5967x over previous
//
#include <hip/hip_runtime.h>
#include <math.h>

#define TPB     128
#define NBATCH  64
#define SPB     16
#define NBLK    (NBATCH*SPB)       // 1024 blocks — the proven topology
#define SROWS   16
#define MM      256
#define AN      257
#define NITER   300
#define NIT1    (NITER+1)
#define SARR    (NBATCH*NIT1)      // ints per counter/flag array
#define RS      264
#define CO(k)   ((k) + ((k) >> 5))

typedef float v4f __attribute__((ext_vector_type(4)));

// ---- contraction-proof IEEE fp32 ops (trajectory bit-identical to round 0/10/12).
__device__ __forceinline__ float mulf(float a, float b) {
  float d; asm("v_mul_f32 %0, %1, %2" : "=v"(d) : "v"(a), "v"(b)); return d;
}
__device__ __forceinline__ float addf(float a, float b) {
  float d; asm("v_add_f32 %0, %1, %2" : "=v"(d) : "v"(a), "v"(b)); return d;
}
__device__ __forceinline__ float subf(float a, float b) {
  float d; asm("v_sub_f32 %0, %1, %2" : "=v"(d) : "v"(a), "v"(b)); return d;
}
__device__ __forceinline__ float fmacf(float acc, float x, float y) {
  asm("v_fmac_f32 %0, %1, %2" : "+v"(acc) : "v"(x), "v"(y)); return acc;
}

// ---- coherent transport: per-access LLC-coherent, cache-bypassing, vectorized.
__device__ __forceinline__ v4f ld4c(const float* p) {
  v4f r;
  asm volatile("global_load_dwordx4 %0, %1, off sc0 sc1" : "=v"(r) : "v"(p) : "memory");
  return r;
}
__device__ __forceinline__ void st4c(float* p, v4f v) {
  asm volatile("global_store_dwordx4 %0, %1, off sc0 sc1" :: "v"(p), "v"(v) : "memory");
}
__device__ __forceinline__ void vmdrain()  { asm volatile("s_waitcnt vmcnt(0)" ::: "memory"); }
__device__ __forceinline__ void drain_all(){ asm volatile("s_waitcnt vmcnt(0) lgkmcnt(0)" ::: "memory"); }

// ---- round-0-proven sync: RELAXED atomics + explicit drains.
#define ALD_F(p)    __hip_atomic_load((p),  __ATOMIC_RELAXED, __HIP_MEMORY_SCOPE_AGENT)
#define AST_F(p,v)  __hip_atomic_store((p), (v), __ATOMIC_RELAXED, __HIP_MEMORY_SCOPE_AGENT)
#define ALD_I(p)    __hip_atomic_load((p),  __ATOMIC_RELAXED, __HIP_MEMORY_SCOPE_AGENT)
#define AST_I(p,v)  __hip_atomic_store((p), (v), __ATOMIC_RELAXED, __HIP_MEMORY_SCOPE_AGENT)
#define AADD_I(p)   __hip_atomic_fetch_add((p), 1, __ATOMIC_RELAXED, __HIP_MEMORY_SCOPE_AGENT)

__global__ void init_ws_kernel(int* __restrict__ z, int n) {
  int i = blockIdx.x * blockDim.x + threadIdx.x;
  if (i < n) z[i] = 0;
}

__device__ __forceinline__ void waitEq(int* p, int target) {
  int tries = 0;
  while (ALD_I(p) < target) {
    __builtin_amdgcn_s_sleep(2);
    if (++tries > (1 << 22)) break;   // hang-safety valve (never expected)
  }
}

// ===== Instruction-contiguous quad layout for pbuf/apbuf/rbuf =====
// Within each wave's 8KB region (8 rows x 256 cols = 512 quads), the quad at
// logical position w = row*64 + chunk*8 + q (row=lane>>3, chunk=lane&7) is
// STORED at slot S = q*64 + lane. Writer instruction q: 64 lanes write
// consecutive 16B = 1KB contiguous (full lines — kills the 2x partial-line
// write amplification). Reader (dot) needs logical quad
// T = P*128 + (lw>>2)*8 + (lw&3) + wid*4; its stored float address is
// offp + (P>>2)*2048 + (P&3)*64 with offp = ((lw&3)+wid*4)*256 + (lw>>2)*4 —
// per instruction also exactly 1KB contiguous. VALUES per lane per step are
// unchanged -> FMA chain bit-identical.
#define QADDR(P) ((size_t)(((P) >> 2) << 11) + (size_t)(((P) & 3) << 6))

// =============== two-wave pair-split dot (chain = round-10/12, proven) ===============
#define W2_FMA16 \
    if (lw < 16) { \
      _Pragma("unroll") \
      for (int cj = 0; cj < 16; ++cj) \
        acc = fmacf(acc, sW[cj * 16 + lw], sW[256 + cj * 16 + lw]); \
    }

#define W2_STEP(D) { \
    asm volatile("s_waitcnt vmcnt(14)" ::: "memory"); \
    *(v4f*)&sW[wix]       = xq[D]; \
    *(v4f*)&sW[256 + wix] = yq[D]; \
    asm volatile("s_waitcnt lgkmcnt(0)" ::: "memory"); \
    xq[D] = ld4c(xp + QADDR(P0 + (D) + 8)); \
    yq[D] = ld4c(yp + QADDR(P0 + (D) + 8)); \
    W2_FMA16 \
    asm volatile("s_waitcnt lgkmcnt(0)" ::: "memory"); }

#define W2_TAIL(D, VM) { \
    asm volatile("s_waitcnt vmcnt(" #VM ")" ::: "memory"); \
    *(v4f*)&sW[wix]       = xq[D]; \
    *(v4f*)&sW[256 + wix] = yq[D]; \
    asm volatile("s_waitcnt lgkmcnt(0)" ::: "memory"); \
    W2_FMA16 \
    asm volatile("s_waitcnt lgkmcnt(0)" ::: "memory"); }

__device__ float dot2w(const float* __restrict__ X, const float* __restrict__ Y,
                       float* __restrict__ sDot, float* __restrict__ sAcc, int tid) {
  const int lw  = tid & 63;
  const int wid = tid >> 6;
  float* sW = sDot + wid * 512;
  const int offp = ((lw & 3) + wid * 4) * 256 + (lw >> 2) * 4;
  const int wix  = (lw >> 2) * 16 + (lw & 3) * 4;
  const float* xp = X + offp;
  const float* yp = Y + offp;
  v4f xq[8], yq[8];
  #pragma unroll
  for (int d = 0; d < 8; ++d) {
    xq[d] = ld4c(xp + QADDR(d));
    yq[d] = ld4c(yp + QADDR(d));
  }
  float acc = 0.0f;
  #pragma unroll 1
  for (int g = 0; g < 15; ++g) {
    const int P0 = g * 8;
    W2_STEP(0) W2_STEP(1) W2_STEP(2) W2_STEP(3)
    W2_STEP(4) W2_STEP(5) W2_STEP(6) W2_STEP(7)
  }
  W2_TAIL(0, 14) W2_TAIL(1, 12) W2_TAIL(2, 10) W2_TAIL(3, 8)
  W2_TAIL(4, 6)  W2_TAIL(5, 4)  W2_TAIL(6, 2)  W2_TAIL(7, 0)

  if (lw < 16) sAcc[wid * 16 + lw] = acc;
  __syncthreads();
  float d0[32];
  #pragma unroll
  for (int o = 0; o < 32; ++o) d0[o] = sAcc[o];
  float C[8];
  #pragma unroll
  for (int l = 0; l < 8; ++l)
    C[l] = addf(addf(d0[l], d0[8 + l]), addf(d0[16 + l], d0[24 + l]));
  float D[4];
  #pragma unroll
  for (int l = 0; l < 4; ++l) D[l] = addf(C[l], C[l + 4]);
  float res = addf(addf(D[0], D[1]), addf(D[2], D[3]));
  __syncthreads();
  return res;
}

// X==Y variant (r.r), 16-deep X-only ring (chain = round-10/12, proven)
#define SQ_FMA16 \
    if (lw < 16) { \
      _Pragma("unroll") \
      for (int cj = 0; cj < 16; ++cj) { \
        float xv = sW[cj * 16 + lw]; \
        acc = fmacf(acc, xv, xv); \
      } \
    }

#define SQ_STEP(D) { \
    asm volatile("s_waitcnt vmcnt(15)" ::: "memory"); \
    *(v4f*)&sW[wix] = xq[D]; \
    asm volatile("s_waitcnt lgkmcnt(0)" ::: "memory"); \
    xq[D] = ld4c(xp + QADDR(P0 + (D) + 16)); \
    SQ_FMA16 \
    asm volatile("s_waitcnt lgkmcnt(0)" ::: "memory"); }

#define SQ_TAIL(D, VM) { \
    asm volatile("s_waitcnt vmcnt(" #VM ")" ::: "memory"); \
    *(v4f*)&sW[wix] = xq[D]; \
    asm volatile("s_waitcnt lgkmcnt(0)" ::: "memory"); \
    SQ_FMA16 \
    asm volatile("s_waitcnt lgkmcnt(0)" ::: "memory"); }

__device__ float dotSq(const float* __restrict__ X,
                       float* __restrict__ sDot, float* __restrict__ sAcc, int tid) {
  const int lw  = tid & 63;
  const int wid = tid >> 6;
  float* sW = sDot + wid * 512;
  const int offp = ((lw & 3) + wid * 4) * 256 + (lw >> 2) * 4;
  const int wix  = (lw >> 2) * 16 + (lw & 3) * 4;
  const float* xp = X + offp;
  v4f xq[16];
  #pragma unroll
  for (int d = 0; d < 16; ++d) xq[d] = ld4c(xp + QADDR(d));
  float acc = 0.0f;
  #pragma unroll 1
  for (int g = 0; g < 7; ++g) {
    const int P0 = g * 16;
    SQ_STEP(0)  SQ_STEP(1)  SQ_STEP(2)  SQ_STEP(3)
    SQ_STEP(4)  SQ_STEP(5)  SQ_STEP(6)  SQ_STEP(7)
    SQ_STEP(8)  SQ_STEP(9)  SQ_STEP(10) SQ_STEP(11)
    SQ_STEP(12) SQ_STEP(13) SQ_STEP(14) SQ_STEP(15)
  }
  SQ_TAIL(0, 15)  SQ_TAIL(1, 14)  SQ_TAIL(2, 13)  SQ_TAIL(3, 12)
  SQ_TAIL(4, 11)  SQ_TAIL(5, 10)  SQ_TAIL(6, 9)   SQ_TAIL(7, 8)
  SQ_TAIL(8, 7)   SQ_TAIL(9, 6)   SQ_TAIL(10, 5)  SQ_TAIL(11, 4)
  SQ_TAIL(12, 3)  SQ_TAIL(13, 2)  SQ_TAIL(14, 1)  SQ_TAIL(15, 0)

  if (lw < 16) sAcc[wid * 16 + lw] = acc;
  __syncthreads();
  float d0[32];
  #pragma unroll
  for (int o = 0; o < 32; ++o) d0[o] = sAcc[o];
  float C[8];
  #pragma unroll
  for (int l = 0; l < 8; ++l)
    C[l] = addf(addf(d0[l], d0[8 + l]), addf(d0[16 + l], d0[24 + l]));
  float D[4];
  #pragma unroll
  for (int l = 0; l < 4; ++l) D[l] = addf(C[l], C[l + 4]);
  float res = addf(addf(D[0], D[1]), addf(D[2], D[3]));
  __syncthreads();
  return res;
}

__launch_bounds__(TPB, 2)   // the proven cap (rounds 0/6/10/12)
__global__ void cg_kernel(const float* __restrict__ alpha,
                          const float* __restrict__ frhs,
                          float* __restrict__ out,
                          int* __restrict__ Z,
                          float* __restrict__ av,
                          float* __restrict__ bv,
                          float* __restrict__ halo,
                          float* __restrict__ pbuf,
                          float* __restrict__ apbuf,
                          float* __restrict__ rbuf)
{
  __shared__ float sP[(SROWS + 2) * RS];
  __shared__ __align__(16) float sDot[1024];
  __shared__ float sAcc[32];

  int* cntP  = Z + 0 * SARR;
  int* cntA  = Z + 1 * SARR;
  int* cntB  = Z + 2 * SARR;
  int* flagA = Z + 3 * SARR;
  int* flagB = Z + 4 * SARR;

  const int tid  = threadIdx.x;
  const int bx   = blockIdx.x;
  const int b    = bx >> 4;
  const int s    = bx & 15;
  const int js   = s * SROWS;
  const int jloc = tid >> 3;
  const int k0   = (tid & 7) << 5;
  const int jg   = js + jloc;
  const int rowb = (jloc + 1) * RS;
  const int bNI  = b * NIT1;
  const size_t gbase = (size_t)b * (MM * MM) + (size_t)jg * MM + k0;
  // wave-region base + lane for the instruction-contiguous publication layout
  const int lane = tid & 63;
  const size_t wbase = (size_t)b * (MM * MM) + (size_t)(js + (tid >> 6) * 8) * MM;

  // ---- coefficients once, reference fp32 rounding order (round-12 verbatim)
  float kl[32], kr[32], kbx[33], dg[32];
  {
    const float* r0 = alpha + (size_t)b * (AN * AN) + (size_t)jg * AN + k0;
    const float* r1 = r0 + AN;
    float a0[33], a1[33];
    #pragma unroll
    for (int i = 0; i < 33; ++i) { a0[i] = r0[i]; a1[i] = r1[i]; }
    #pragma unroll
    for (int i = 0; i < 33; ++i) kbx[i] = expf(0.5f * (a0[i] + a1[i]));
    #pragma unroll
    for (int i = 0; i < 32; ++i) {
      const int kg = k0 + i;
      float vkl = expf(0.5f * (a0[i] + a0[i + 1]));
      float vkr = (jg < MM - 1) ? expf(0.5f * (a1[i] + a1[i + 1])) : 0.0f;
      float vkb = (kg > 0)      ? kbx[i]     : 0.0f;
      float vkt = (kg < MM - 1) ? kbx[i + 1] : 0.0f;
      float d = ((vkl + vkr) + vkb) + vkt;
      if (jg == 0) d += vkl;
      kl[i] = vkl; kr[i] = vkr; dg[i] = d;
    }
  }

  float uu[32], rr[32], pp[32], Ap[32];
  {
    const float* fB = frhs + (size_t)jg * MM + k0;
    #pragma unroll
    for (int i = 0; i < 32; ++i) {
      float v = fB[i];
      uu[i] = 0.0f; rr[i] = v; pp[i] = v;
      sP[rowb + CO(k0 + i)] = v;
    }
    #pragma unroll
    for (int q = 0; q < 8; ++q) {
      v4f pv; pv[0] = pp[4*q]; pv[1] = pp[4*q+1]; pv[2] = pp[4*q+2]; pv[3] = pp[4*q+3];
      st4c(&pbuf[wbase + (size_t)((q * 64 + lane) << 2)], pv);
      st4c(&rbuf[wbase + (size_t)((q * 64 + lane) << 2)], pv);
    }
  }
  float* myhalo = halo + (size_t)bx * 512;
  if (jloc == 0) {
    #pragma unroll
    for (int q = 0; q < 8; ++q) {
      v4f hv; hv[0] = pp[4*q]; hv[1] = pp[4*q+1]; hv[2] = pp[4*q+2]; hv[3] = pp[4*q+3];
      st4c(&myhalo[k0 + 4 * q], hv);
    }
  }
  if (jloc == SROWS - 1) {
    #pragma unroll
    for (int q = 0; q < 8; ++q) {
      v4f hv; hv[0] = pp[4*q]; hv[1] = pp[4*q+1]; hv[2] = pp[4*q+2]; hv[3] = pp[4*q+3];
      st4c(&myhalo[256 + k0 + 4 * q], hv);
    }
  }
  drain_all();
  __syncthreads();
  if (tid == 0) AADD_I(&cntP[bNI + 0]);

  float gamma_red = 0.0f;   // uniform across the s==0 block after dots

  for (int it = 1; it <= NITER; ++it) {
    // ---- phase A: wait p ready, stage halos, stencil, publish Ap
    if (tid == 0) waitEq(&cntP[bNI + it - 1], SPB);
    __syncthreads();
    if (jloc == 0) {
      if (s > 0) {
        float* nh = halo + (size_t)(bx - 1) * 512 + 256;
        v4f hv[8];
        #pragma unroll
        for (int q = 0; q < 8; ++q) hv[q] = ld4c(&nh[k0 + 4 * q]);
        vmdrain();
        #pragma unroll
        for (int q = 0; q < 8; ++q) {
          sP[CO(k0 + 4*q)]     = hv[q][0];
          sP[CO(k0 + 4*q + 1)] = hv[q][1];
          sP[CO(k0 + 4*q + 2)] = hv[q][2];
          sP[CO(k0 + 4*q + 3)] = hv[q][3];
        }
      } else {
        #pragma unroll
        for (int i = 0; i < 32; ++i) sP[CO(k0 + i)] = 0.0f;
      }
    }
    if (jloc == SROWS - 1) {
      if (s < SPB - 1) {
        float* nh = halo + (size_t)(bx + 1) * 512;
        v4f hv[8];
        #pragma unroll
        for (int q = 0; q < 8; ++q) hv[q] = ld4c(&nh[k0 + 4 * q]);
        vmdrain();
        #pragma unroll
        for (int q = 0; q < 8; ++q) {
          sP[(SROWS + 1) * RS + CO(k0 + 4*q)]     = hv[q][0];
          sP[(SROWS + 1) * RS + CO(k0 + 4*q + 1)] = hv[q][1];
          sP[(SROWS + 1) * RS + CO(k0 + 4*q + 2)] = hv[q][2];
          sP[(SROWS + 1) * RS + CO(k0 + 4*q + 3)] = hv[q][3];
        }
      } else {
        #pragma unroll
        for (int i = 0; i < 32; ++i) sP[(SROWS + 1) * RS + CO(k0 + i)] = 0.0f;
      }
    }
    __syncthreads();

    {
      v4f apv;
      #pragma unroll
      for (int i = 0; i < 32; ++i) {
        const int kg = k0 + i;
        float pc = pp[i];
        float pd = sP[rowb - RS + CO(kg)];
        float pu = sP[rowb + RS + CO(kg)];
        float pl = (i > 0) ? pp[i - 1]
                           : ((k0 > 0) ? sP[rowb + CO(k0 - 1)] : 0.0f);
        float pr = (i < 31) ? pp[i + 1]
                            : ((kg < MM - 1) ? sP[rowb + CO(k0 + 32)] : 0.0f);
        float vkb = (kg > 0)      ? kbx[i]     : 0.0f;
        float vkt = (kg < MM - 1) ? kbx[i + 1] : 0.0f;
        float t = mulf(dg[i], pc);
        t = subf(t, mulf(kl[i], pd));
        t = subf(t, mulf(kr[i], pu));
        t = subf(t, mulf(vkb, pl));
        t = subf(t, mulf(vkt, pr));
        float ap = mulf(65536.0f, t);
        Ap[i] = ap;
        apv[i & 3] = ap;
        if ((i & 3) == 3)
          st4c(&apbuf[wbase + (size_t)((((i >> 2) * 64) + lane) << 2)], apv);
      }
    }
    drain_all();
    __syncthreads();
    if (tid == 0) AADD_I(&cntA[bNI + it]);

    // ---- reducer (block s==0, both waves): alpha = gamma / (p.Ap)
    if (s == 0) {
      if (tid == 0) waitEq(&cntA[bNI + it], SPB);
      __syncthreads();
      const float* Pb  = pbuf  + (size_t)b * (MM * MM);
      const float* APb = apbuf + (size_t)b * (MM * MM);
      const float* Rb  = rbuf  + (size_t)b * (MM * MM);
      if (it == 1) gamma_red = dotSq(Rb, sDot, sAcc, tid);
      float pap = dot2w(Pb, APb, sDot, sAcc, tid);
      if (tid == 0) {
        AST_F(&av[bNI + it], gamma_red / pap);
        vmdrain();
        AST_I(&flagA[bNI + it], 1);
      }
    }

    // ---- phase B: x += a p ; r -= a Ap ; publish r
    if (tid == 0) waitEq(&flagA[bNI + it], 1);
    __syncthreads();
    float alf = ALD_F(&av[bNI + it]);
    {
      v4f rv;
      #pragma unroll
      for (int i = 0; i < 32; ++i) {
        uu[i] = addf(uu[i], mulf(alf, pp[i]));
        rr[i] = subf(rr[i], mulf(alf, Ap[i]));
        rv[i & 3] = rr[i];
        if ((i & 3) == 3)
          st4c(&rbuf[wbase + (size_t)((((i >> 2) * 64) + lane) << 2)], rv);
      }
    }
    drain_all();
    __syncthreads();
    if (tid == 0) AADD_I(&cntB[bNI + it]);

    // ---- reducer (block s==0, both waves): beta = gamma'/gamma
    if (s == 0) {
      if (tid == 0) waitEq(&cntB[bNI + it], SPB);
      __syncthreads();
      const float* Rb = rbuf + (size_t)b * (MM * MM);
      float g2 = dotSq(Rb, sDot, sAcc, tid);
      if (tid == 0) {
        AST_F(&bv[bNI + it], g2 / gamma_red);
        vmdrain();
        AST_I(&flagB[bNI + it], 1);
      }
      gamma_red = g2;
    }

    // ---- phase C: p = r + b p ; publish p + halos
    if (tid == 0) waitEq(&flagB[bNI + it], 1);
    __syncthreads();
    float bet = ALD_F(&bv[bNI + it]);
    {
      v4f pv;
      #pragma unroll
      for (int i = 0; i < 32; ++i) {
        float pn = addf(rr[i], mulf(bet, pp[i]));
        pp[i] = pn;
        sP[rowb + CO(k0 + i)] = pn;
        pv[i & 3] = pn;
        if ((i & 3) == 3)
          st4c(&pbuf[wbase + (size_t)((((i >> 2) * 64) + lane) << 2)], pv);
      }
    }
    if (jloc == 0) {
      #pragma unroll
      for (int q = 0; q < 8; ++q) {
        v4f hv; hv[0] = pp[4*q]; hv[1] = pp[4*q+1]; hv[2] = pp[4*q+2]; hv[3] = pp[4*q+3];
        st4c(&myhalo[k0 + 4 * q], hv);
      }
    }
    if (jloc == SROWS - 1) {
      #pragma unroll
      for (int q = 0; q < 8; ++q) {
        v4f hv; hv[0] = pp[4*q]; hv[1] = pp[4*q+1]; hv[2] = pp[4*q+2]; hv[3] = pp[4*q+3];
        st4c(&myhalo[256 + k0 + 4 * q], hv);
      }
    }
    drain_all();
    __syncthreads();
    if (tid == 0) AADD_I(&cntP[bNI + it]);
  }

  float* oB = out + gbase;
  #pragma unroll
  for (int i = 0; i < 32; ++i) oB[i] = uu[i];
}

extern "C" void kernel_launch(void* const* d_in, const int* in_sizes, int n_in,
                              void* d_out, int out_size, void* d_ws, size_t ws_size,
                              hipStream_t stream) {
  const float* alpha = (const float*)d_in[0];   // (64, 257, 257) fp32
  const float* frhs  = (const float*)d_in[1];   // (256, 256) fp32
  float* out = (float*)d_out;                   // (64, 256, 256) fp32

  char* ws = (char*)d_ws;
  int*   Z    = (int*)ws;                               // 5 int arrays [64][301]
  float* av   = (float*)(ws + (size_t)5 * SARR * 4);
  float* bv   = (float*)(ws + (size_t)6 * SARR * 4);
  size_t ZR   = ((size_t)7 * SARR * 4 + 4095) & ~(size_t)4095;
  float* halo  = (float*)(ws + ZR);                     // 2 MB
  float* pbuf  = (float*)(ws + ZR + (size_t)NBLK * 512 * 4);
  float* apbuf = pbuf  + (size_t)NBATCH * MM * MM;      // 16 MB each
  float* rbuf  = apbuf + (size_t)NBATCH * MM * MM;

  int nz = 5 * SARR;
  hipLaunchKernelGGL(init_ws_kernel, dim3((nz + 255) / 256), dim3(256), 0, stream,
                     Z, nz);
  hipLaunchKernelGGL(cg_kernel, dim3(NBLK), dim3(TPB), 0, stream,
                     alpha, frhs, out, Z, av, bv, halo, pbuf, apbuf, rbuf);
}